// Round 2
// baseline (556.922 us; speedup 1.0000x reference)
//
#include <hip/hip_runtime.h>

// WindowAttention: B=8, C=128, H=W=256, ws=8, heads=4, d=32, n=64 tokens/window
// One block = one window (8192 blocks, 256 thr = 4 waves). Wave h owns head h.
// All GEMMs via v_mfma_f32_16x16x32_bf16, f32 accumulation; softmax/bias/output f32.
// LDS = 16 KiB total, phase-overlaid:
//   [0,16K): Xt[64][128]bf16 -> per-wave 4KiB scratch (K/Q/V/P sequential)
//            -> Ot[64][128]bf16 -> Ystage[32][128]f32 (two token-halves)

#define HH    256
#define WWID  256
#define SCALE 0.17677669529663687f

typedef float  f32x4  __attribute__((ext_vector_type(4)));
typedef __bf16 bf16x8 __attribute__((ext_vector_type(8)));
typedef short  s16x4  __attribute__((ext_vector_type(4)));
typedef unsigned short ushort_t;

__device__ __forceinline__ ushort_t f2bf(float x) {
  unsigned u = __float_as_uint(x);
  u += 0x7fffu + ((u >> 16) & 1u);        // round-to-nearest-even
  return (ushort_t)(u >> 16);
}

__global__ void prep_weights(const float* __restrict__ wqkv,
                             const float* __restrict__ wproj,
                             ushort_t* __restrict__ wbf) {
  int i = blockIdx.x * 256 + threadIdx.x;          // 65536 total
  float v = (i < 49152) ? wqkv[i] : wproj[i - 49152];
  wbf[i] = f2bf(v);
}

__global__ __launch_bounds__(256, 4)
void winattn_main(const float* __restrict__ x,
                  const ushort_t* __restrict__ wqkv,   // [384][128] bf16
                  const ushort_t* __restrict__ wproj,  // [128][128] bf16
                  const float* __restrict__ bproj,
                  float* __restrict__ out) {
  __shared__ __align__(16) char smem[16384];

  const int tid  = threadIdx.x;
  const int lane = tid & 63;
  const int wv   = tid >> 6;       // wave id == head id
  const int l15  = lane & 15;
  const int l4   = lane >> 4;

  // XCD-aware swizzle: XCD k owns batch k; adjacent windows (sharing 64B
  // lines of x/out) land on the same XCD, adjacent in dispatch time.
  const int bid = blockIdx.x;
  const int win = ((bid & 7) << 10) | (bid >> 3);
  const int b   = win >> 10;
  const int wy  = (win >> 5) & 31;
  const int wx  = win & 31;
  const int gy0 = wy * 8, gx0 = wx * 8;

  // ---------------- Phase A: load window -> Xt[tok][c] bf16 (swizzled) ----------------
  #pragma unroll
  for (int it = 0; it < 4; ++it) {
    int idx   = tid + it * 256;        // 1024 tasks: (cpair 64) x (ty 8) x (tx4 2)
    int cpair = idx >> 4;
    int r     = idx & 15;
    int ty    = r >> 1, tx4 = r & 1;
    const float* px = x + (((size_t)(b * 128 + 2 * cpair) * HH + gy0 + ty) * WWID + gx0 + tx4 * 4);
    float4 v0 = *(const float4*)px;
    float4 v1 = *(const float4*)(px + (size_t)HH * WWID);
    float a0[4] = {v0.x, v0.y, v0.z, v0.w};
    float a1[4] = {v1.x, v1.y, v1.z, v1.w};
    #pragma unroll
    for (int i = 0; i < 4; ++i) {
      int tok = ty * 8 + tx4 * 4 + i;
      unsigned wword = (unsigned)f2bf(a0[i]) | ((unsigned)f2bf(a1[i]) << 16);
      int byte = (tok * 256 + cpair * 4) ^ ((tok & 7) << 4);
      *(unsigned*)(smem + byte) = wword;
    }
  }
  __syncthreads();

  // A-fragments of Xt into registers (shared by all QKV GEMMs of this wave)
  bf16x8 af[4][4];   // [mtile][ktile]
  #pragma unroll
  for (int mt = 0; mt < 4; ++mt)
    #pragma unroll
    for (int kt = 0; kt < 4; ++kt) {
      int tok  = mt * 16 + l15;
      int byte = (tok * 256 + (kt * 32 + l4 * 8) * 2) ^ ((tok & 7) << 4);
      af[mt][kt] = *(const bf16x8*)(smem + byte);
    }
  __syncthreads();   // Xt dead -> [0,16K) becomes per-wave scratch

  const int scr = wv * 4096;          // private 4 KiB per wave
  bf16x8 bk[4], aq[4], bv[2][2];

  // ---------------- Phase B: QKV for head wv (scratch reused K->Q->V) ----------------
  // K (weight rows 128..255)
  #pragma unroll
  for (int nt2 = 0; nt2 < 2; ++nt2) {
    int orow0 = 128 + wv * 32 + nt2 * 16;
    f32x4 acc[4] = {};
    #pragma unroll
    for (int kt = 0; kt < 4; ++kt) {
      bf16x8 bf = *(const bf16x8*)(wqkv + (size_t)(orow0 + l15) * 128 + kt * 32 + l4 * 8);
      #pragma unroll
      for (int mt = 0; mt < 4; ++mt)
        acc[mt] = __builtin_amdgcn_mfma_f32_16x16x32_bf16(af[mt][kt], bf, acc[mt], 0, 0, 0);
    }
    int dloc = nt2 * 16 + l15;
    #pragma unroll
    for (int mt = 0; mt < 4; ++mt)
      #pragma unroll
      for (int r = 0; r < 4; ++r) {
        int tok  = mt * 16 + l4 * 4 + r;
        int byte = scr + ((tok * 64 + dloc * 2) ^ ((tok & 3) << 4));
        *(ushort_t*)(smem + byte) = f2bf(acc[mt][r]);
      }
  }
  #pragma unroll
  for (int mtS = 0; mtS < 4; ++mtS) {      // K B-fragments
    int m    = mtS * 16 + l15;
    int byte = scr + ((m * 64 + l4 * 16) ^ ((m & 3) << 4));
    bk[mtS] = *(const bf16x8*)(smem + byte);
  }
  // Q (weight rows 0..127), SCALE folded in
  #pragma unroll
  for (int nt2 = 0; nt2 < 2; ++nt2) {
    int orow0 = wv * 32 + nt2 * 16;
    f32x4 acc[4] = {};
    #pragma unroll
    for (int kt = 0; kt < 4; ++kt) {
      bf16x8 bf = *(const bf16x8*)(wqkv + (size_t)(orow0 + l15) * 128 + kt * 32 + l4 * 8);
      #pragma unroll
      for (int mt = 0; mt < 4; ++mt)
        acc[mt] = __builtin_amdgcn_mfma_f32_16x16x32_bf16(af[mt][kt], bf, acc[mt], 0, 0, 0);
    }
    int dloc = nt2 * 16 + l15;
    #pragma unroll
    for (int mt = 0; mt < 4; ++mt)
      #pragma unroll
      for (int r = 0; r < 4; ++r) {
        int tok  = mt * 16 + l4 * 4 + r;
        int byte = scr + ((tok * 64 + dloc * 2) ^ ((tok & 3) << 4));
        *(ushort_t*)(smem + byte) = f2bf(acc[mt][r] * SCALE);
      }
  }
  #pragma unroll
  for (int t = 0; t < 4; ++t) {            // Q A-fragments (t = hf*2+qt)
    int tok  = t * 16 + l15;
    int byte = scr + ((tok * 64 + l4 * 16) ^ ((tok & 3) << 4));
    aq[t] = *(const bf16x8*)(smem + byte);
  }
  // V (weight rows 256..383), stored transposed [32 d][64 tok]
  #pragma unroll
  for (int nt2 = 0; nt2 < 2; ++nt2) {
    int orow0 = 256 + wv * 32 + nt2 * 16;
    f32x4 acc[4] = {};
    #pragma unroll
    for (int kt = 0; kt < 4; ++kt) {
      bf16x8 bf = *(const bf16x8*)(wqkv + (size_t)(orow0 + l15) * 128 + kt * 32 + l4 * 8);
      #pragma unroll
      for (int mt = 0; mt < 4; ++mt)
        acc[mt] = __builtin_amdgcn_mfma_f32_16x16x32_bf16(af[mt][kt], bf, acc[mt], 0, 0, 0);
    }
    int dloc = nt2 * 16 + l15;
    #pragma unroll
    for (int mt = 0; mt < 4; ++mt) {
      int tok0 = mt * 16 + l4 * 4;
      s16x4 wv4;
      #pragma unroll
      for (int r = 0; r < 4; ++r) wv4[r] = (short)f2bf(acc[mt][r]);
      int byte = scr + ((dloc * 128 + tok0 * 2) ^ ((dloc & 7) << 4));
      *(s16x4*)(smem + byte) = wv4;
    }
  }
  #pragma unroll
  for (int vt = 0; vt < 2; ++vt)           // V B-fragments
    #pragma unroll
    for (int kt = 0; kt < 2; ++kt) {
      int d    = vt * 16 + l15;
      int byte = scr + ((d * 128 + (kt * 32 + l4 * 8) * 2) ^ ((d & 7) << 4));
      bv[vt][kt] = *(const bf16x8*)(smem + byte);
    }

  // ---------------- Phase C: attention (two 32-row halves; P overlays scratch) ----------------
  f32x4 oacc[2][2][2] = {};   // [half][row-tile][d-tile]
  #pragma unroll
  for (int hf = 0; hf < 2; ++hf) {
    #pragma unroll
    for (int qt = 0; qt < 2; ++qt) {
      f32x4 s[4];
      #pragma unroll
      for (int mtS = 0; mtS < 4; ++mtS) {
        f32x4 z = {0.f, 0.f, 0.f, 0.f};
        s[mtS] = __builtin_amdgcn_mfma_f32_16x16x32_bf16(aq[hf * 2 + qt], bk[mtS], z, 0, 0, 0);
      }
      #pragma unroll
      for (int r = 0; r < 4; ++r) {
        float v0 = s[0][r], v1 = s[1][r], v2 = s[2][r], v3 = s[3][r];
        float mx = fmaxf(fmaxf(v0, v1), fmaxf(v2, v3));
        mx = fmaxf(mx, __shfl_xor(mx, 1));
        mx = fmaxf(mx, __shfl_xor(mx, 2));
        mx = fmaxf(mx, __shfl_xor(mx, 4));
        mx = fmaxf(mx, __shfl_xor(mx, 8));
        float e0 = __expf(v0 - mx), e1 = __expf(v1 - mx);
        float e2 = __expf(v2 - mx), e3 = __expf(v3 - mx);
        float sm = e0 + e1 + e2 + e3;
        sm += __shfl_xor(sm, 1);
        sm += __shfl_xor(sm, 2);
        sm += __shfl_xor(sm, 4);
        sm += __shfl_xor(sm, 8);
        float inv = 1.0f / sm;
        int nl = qt * 16 + l4 * 4 + r;          // local row 0..31
        int sw = (nl & 7) << 4;
        int rb = scr + nl * 128;
        *(ushort_t*)(smem + (((nl * 128 + (0 * 16 + l15) * 2)) ^ sw) + scr - scr + scr) = f2bf(e0 * inv);
        // (expanded below without the no-op arithmetic)
        (void)rb;
        *(ushort_t*)(smem + scr + (((nl * 128 + (1 * 16 + l15) * 2)) ^ sw)) = f2bf(e1 * inv);
        *(ushort_t*)(smem + scr + (((nl * 128 + (2 * 16 + l15) * 2)) ^ sw)) = f2bf(e2 * inv);
        *(ushort_t*)(smem + scr + (((nl * 128 + (3 * 16 + l15) * 2)) ^ sw)) = f2bf(e3 * inv);
      }
    }
    // O += P V  (accumulate in registers)
    #pragma unroll
    for (int kt = 0; kt < 2; ++kt)
      #pragma unroll
      for (int rt = 0; rt < 2; ++rt) {
        int nl   = rt * 16 + l15;
        int byte = scr + ((nl * 128 + (kt * 32 + l4 * 8) * 2) ^ ((nl & 7) << 4));
        bf16x8 ap = *(const bf16x8*)(smem + byte);
        #pragma unroll
        for (int vt = 0; vt < 2; ++vt)
          oacc[hf][rt][vt] =
              __builtin_amdgcn_mfma_f32_16x16x32_bf16(ap, bv[vt][kt], oacc[hf][rt][vt], 0, 0, 0);
      }
  }
  __syncthreads();   // scratch dead everywhere -> overlay Ot

  // write Ot[64 tok][128 c] bf16 at base 0
  #pragma unroll
  for (int hf = 0; hf < 2; ++hf)
    #pragma unroll
    for (int rt = 0; rt < 2; ++rt)
      #pragma unroll
      for (int vt = 0; vt < 2; ++vt)
        #pragma unroll
        for (int r = 0; r < 4; ++r) {
          int tok  = hf * 32 + rt * 16 + l4 * 4 + r;
          int c    = wv * 32 + vt * 16 + l15;
          int byte = (tok * 256 + c * 2) ^ ((tok & 7) << 4);
          *(ushort_t*)(smem + byte) = f2bf(oacc[hf][rt][vt][r]);
        }
  __syncthreads();

  // ---------------- Phase D: proj GEMM (acc in regs) ----------------
  bf16x8 ao[4][4];
  #pragma unroll
  for (int mt = 0; mt < 4; ++mt)
    #pragma unroll
    for (int kt = 0; kt < 4; ++kt) {
      int tok  = mt * 16 + l15;
      int byte = (tok * 256 + (kt * 32 + l4 * 8) * 2) ^ ((tok & 7) << 4);
      ao[mt][kt] = *(const bf16x8*)(smem + byte);
    }
  __syncthreads();   // Ot dead -> overlay Ystage halves

  f32x4 pacc[2][4];  // [o-tile][tok-tile]
  #pragma unroll
  for (int i = 0; i < 2; ++i) {
    #pragma unroll
    for (int mt = 0; mt < 4; ++mt) pacc[i][mt] = (f32x4){0.f, 0.f, 0.f, 0.f};
    int orow0 = (wv * 2 + i) * 16;
    #pragma unroll
    for (int kt = 0; kt < 4; ++kt) {
      bf16x8 bf = *(const bf16x8*)(wproj + (size_t)(orow0 + l15) * 128 + kt * 32 + l4 * 8);
      #pragma unroll
      for (int mt = 0; mt < 4; ++mt)
        pacc[i][mt] = __builtin_amdgcn_mfma_f32_16x16x32_bf16(ao[mt][kt], bf, pacc[i][mt], 0, 0, 0);
    }
  }

  // ---------------- Phase E: stage f32 + bias + coalesced writeout, 2 token-halves ----------------
  #pragma unroll
  for (int half = 0; half < 2; ++half) {
    if (half) __syncthreads();     // previous half's reads done before overwrite
    #pragma unroll
    for (int i = 0; i < 2; ++i) {
      int o = (wv * 2 + i) * 16 + l15;
      #pragma unroll
      for (int m2 = 0; m2 < 2; ++m2)
        #pragma unroll
        for (int r = 0; r < 4; ++r) {
          int ytok = m2 * 16 + l4 * 4 + r;        // 0..31 within half
          int byte = (ytok * 512 + o * 4) ^ ((ytok & 7) << 4);
          *(float*)(smem + byte) = pacc[i][half * 2 + m2][r];
        }
    }
    __syncthreads();
    #pragma unroll
    for (int it = 0; it < 2; ++it) {
      int idx = tid + it * 256;       // 512 tasks: (o 128) x (ty 4)
      int o   = idx & 127;
      int ty  = idx >> 7;             // 0..3
      float bias = bproj[o];
      float vals[8];
      #pragma unroll
      for (int tx = 0; tx < 8; ++tx) {
        int ytok = ty * 8 + tx;
        int byte = (ytok * 512 + o * 4) ^ ((ytok & 7) << 4);
        vals[tx] = *(const float*)(smem + byte) + bias;
      }
      int row = half * 4 + ty;
      float4 f0 = {vals[0], vals[1], vals[2], vals[3]};
      float4 f1 = {vals[4], vals[5], vals[6], vals[7]};
      float* po = out + (((size_t)(b * 128 + o) * HH + gy0 + row) * WWID + gx0);
      *(float4*)po       = f0;
      *(float4*)(po + 4) = f1;
    }
  }
}

extern "C" void kernel_launch(void* const* d_in, const int* in_sizes, int n_in,
                              void* d_out, int out_size, void* d_ws, size_t ws_size,
                              hipStream_t stream) {
  const float* x     = (const float*)d_in[0];
  const float* wqkv  = (const float*)d_in[1];
  const float* wproj = (const float*)d_in[2];
  const float* bproj = (const float*)d_in[3];
  float* out = (float*)d_out;

  ushort_t* wbf = (ushort_t*)d_ws;   // 65536 bf16 = 128 KiB scratch
  prep_weights<<<256, 256, 0, stream>>>(wqkv, wproj, wbf);
  winattn_main<<<8192, 256, 0, stream>>>(x, wbf, wbf + 49152, bproj, out);
}

// Round 3
// 415.446 us; speedup vs baseline: 1.3405x; 1.3405x over previous
//
#include <hip/hip_runtime.h>

// WindowAttention: B=8, C=128, H=W=256, ws=8, heads=4, d=32, n=64 tokens/window
// One block = one window (8192 blocks, 256 thr = 4 waves). Wave h owns head h.
// All GEMMs via v_mfma_f32_16x16x32_bf16, f32 accumulation; softmax/bias/output f32.
// LDS = 32 KiB:
//   [0,16K):   Xt[64][128]bf16 (live A->B)  -> Ot[64][128]bf16 (C->D)
//   [16K,32K): per-wave 4KiB scratch (K/Q/V/P sequential, B->C)
//              -> Ystage[32][128]f32 halves (E)

#define HH    256
#define WWID  256
#define SCALE 0.17677669529663687f

typedef float  f32x4  __attribute__((ext_vector_type(4)));
typedef __bf16 bf16x8 __attribute__((ext_vector_type(8)));
typedef short  s16x4  __attribute__((ext_vector_type(4)));
typedef unsigned short ushort_t;

#define SCR_BASE 16384

__device__ __forceinline__ ushort_t f2bf(float x) {
  unsigned u = __float_as_uint(x);
  u += 0x7fffu + ((u >> 16) & 1u);        // round-to-nearest-even
  return (ushort_t)(u >> 16);
}

__global__ void prep_weights(const float* __restrict__ wqkv,
                             const float* __restrict__ wproj,
                             ushort_t* __restrict__ wbf) {
  int i = blockIdx.x * 256 + threadIdx.x;          // 65536 total
  float v = (i < 49152) ? wqkv[i] : wproj[i - 49152];
  wbf[i] = f2bf(v);
}

__global__ __launch_bounds__(256) __attribute__((amdgpu_waves_per_eu(4, 4)))
void winattn_main(const float* __restrict__ x,
                  const ushort_t* __restrict__ wqkv,   // [384][128] bf16
                  const ushort_t* __restrict__ wproj,  // [128][128] bf16
                  const float* __restrict__ bproj,
                  float* __restrict__ out) {
  __shared__ __align__(16) char smem[32768];

  const int tid  = threadIdx.x;
  const int lane = tid & 63;
  const int wv   = tid >> 6;       // wave id == head id
  const int l15  = lane & 15;
  const int l4   = lane >> 4;

  // XCD-aware swizzle: XCD k owns batch k; horizontally adjacent windows
  // (sharing 64B lines of x/out) are 8 apart in bid -> same XCD, adjacent in time.
  const int bid = blockIdx.x;
  const int win = ((bid & 7) << 10) | (bid >> 3);
  const int b   = win >> 10;
  const int wy  = (win >> 5) & 31;
  const int wx  = win & 31;
  const int gy0 = wy * 8, gx0 = wx * 8;

  // ---------------- Phase A: load window -> Xt[tok][c] bf16 (swizzled) ----------------
  #pragma unroll
  for (int it = 0; it < 4; ++it) {
    int idx   = tid + it * 256;        // 1024 tasks: (cpair 64) x (ty 8) x (tx4 2)
    int cpair = idx >> 4;
    int r     = idx & 15;
    int ty    = r >> 1, tx4 = r & 1;
    const float* px = x + (((size_t)(b * 128 + 2 * cpair) * HH + gy0 + ty) * WWID + gx0 + tx4 * 4);
    float4 v0 = *(const float4*)px;
    float4 v1 = *(const float4*)(px + (size_t)HH * WWID);
    float a0[4] = {v0.x, v0.y, v0.z, v0.w};
    float a1[4] = {v1.x, v1.y, v1.z, v1.w};
    #pragma unroll
    for (int i = 0; i < 4; ++i) {
      int tok = ty * 8 + tx4 * 4 + i;
      unsigned wword = (unsigned)f2bf(a0[i]) | ((unsigned)f2bf(a1[i]) << 16);
      int byte = (tok * 256 + cpair * 4) ^ ((tok & 7) << 4);
      *(unsigned*)(smem + byte) = wword;
    }
  }
  __syncthreads();

  const int scr = SCR_BASE + wv * 4096;   // private 4 KiB per wave
  bf16x8 bk[4], aq[4], bv[2][2];

  // A-fragment of Xt, re-read per use (Xt stays live through phase B)
  #define XT_AFRAG(mt, kt) \
    (*(const bf16x8*)(smem + ((((mt) * 16 + l15) * 256 + ((kt) * 32 + l4 * 8) * 2) ^ \
                              ((((mt) * 16 + l15) & 7) << 4))))

  // ---------------- Phase B: QKV for head wv (scratch reused K->Q->V) ----------------
  // K (weight rows 128..255), token-major [64][32]
  #pragma unroll
  for (int nt2 = 0; nt2 < 2; ++nt2) {
    int orow0 = 128 + wv * 32 + nt2 * 16;
    f32x4 acc[4] = {};
    #pragma unroll
    for (int kt = 0; kt < 4; ++kt) {
      bf16x8 bf = *(const bf16x8*)(wqkv + (size_t)(orow0 + l15) * 128 + kt * 32 + l4 * 8);
      #pragma unroll
      for (int mt = 0; mt < 4; ++mt)
        acc[mt] = __builtin_amdgcn_mfma_f32_16x16x32_bf16(XT_AFRAG(mt, kt), bf, acc[mt], 0, 0, 0);
    }
    int dloc = nt2 * 16 + l15;
    #pragma unroll
    for (int mt = 0; mt < 4; ++mt)
      #pragma unroll
      for (int r = 0; r < 4; ++r) {
        int tok  = mt * 16 + l4 * 4 + r;
        int byte = scr + ((tok * 64 + dloc * 2) ^ ((tok & 3) << 4));
        *(ushort_t*)(smem + byte) = f2bf(acc[mt][r]);
      }
  }
  #pragma unroll
  for (int mtS = 0; mtS < 4; ++mtS) {      // K B-fragments
    int m    = mtS * 16 + l15;
    int byte = scr + ((m * 64 + l4 * 16) ^ ((m & 3) << 4));
    bk[mtS] = *(const bf16x8*)(smem + byte);
  }
  // Q (weight rows 0..127), SCALE folded in
  #pragma unroll
  for (int nt2 = 0; nt2 < 2; ++nt2) {
    int orow0 = wv * 32 + nt2 * 16;
    f32x4 acc[4] = {};
    #pragma unroll
    for (int kt = 0; kt < 4; ++kt) {
      bf16x8 bf = *(const bf16x8*)(wqkv + (size_t)(orow0 + l15) * 128 + kt * 32 + l4 * 8);
      #pragma unroll
      for (int mt = 0; mt < 4; ++mt)
        acc[mt] = __builtin_amdgcn_mfma_f32_16x16x32_bf16(XT_AFRAG(mt, kt), bf, acc[mt], 0, 0, 0);
    }
    int dloc = nt2 * 16 + l15;
    #pragma unroll
    for (int mt = 0; mt < 4; ++mt)
      #pragma unroll
      for (int r = 0; r < 4; ++r) {
        int tok  = mt * 16 + l4 * 4 + r;
        int byte = scr + ((tok * 64 + dloc * 2) ^ ((tok & 3) << 4));
        *(ushort_t*)(smem + byte) = f2bf(acc[mt][r] * SCALE);
      }
  }
  #pragma unroll
  for (int t = 0; t < 4; ++t) {            // Q A-fragments (t = hf*2+qt)
    int tok  = t * 16 + l15;
    int byte = scr + ((tok * 64 + l4 * 16) ^ ((tok & 3) << 4));
    aq[t] = *(const bf16x8*)(smem + byte);
  }
  // V (weight rows 256..383), stored transposed [32 d][64 tok]
  #pragma unroll
  for (int nt2 = 0; nt2 < 2; ++nt2) {
    int orow0 = 256 + wv * 32 + nt2 * 16;
    f32x4 acc[4] = {};
    #pragma unroll
    for (int kt = 0; kt < 4; ++kt) {
      bf16x8 bf = *(const bf16x8*)(wqkv + (size_t)(orow0 + l15) * 128 + kt * 32 + l4 * 8);
      #pragma unroll
      for (int mt = 0; mt < 4; ++mt)
        acc[mt] = __builtin_amdgcn_mfma_f32_16x16x32_bf16(XT_AFRAG(mt, kt), bf, acc[mt], 0, 0, 0);
    }
    int dloc = nt2 * 16 + l15;
    #pragma unroll
    for (int mt = 0; mt < 4; ++mt) {
      int tok0 = mt * 16 + l4 * 4;
      s16x4 wv4;
      #pragma unroll
      for (int r = 0; r < 4; ++r) wv4[r] = (short)f2bf(acc[mt][r]);
      int byte = scr + ((dloc * 128 + tok0 * 2) ^ ((dloc & 7) << 4));
      *(s16x4*)(smem + byte) = wv4;
    }
  }
  #pragma unroll
  for (int vt = 0; vt < 2; ++vt)           // V B-fragments
    #pragma unroll
    for (int kt = 0; kt < 2; ++kt) {
      int d    = vt * 16 + l15;
      int byte = scr + ((d * 128 + (kt * 32 + l4 * 8) * 2) ^ ((d & 7) << 4));
      bv[vt][kt] = *(const bf16x8*)(smem + byte);
    }

  // ---------------- Phase C: attention (two 32-row halves; P overlays scratch) ----------------
  f32x4 oacc[2][2][2] = {};   // [half][row-tile][d-tile]
  #pragma unroll
  for (int hf = 0; hf < 2; ++hf) {
    #pragma unroll
    for (int qt = 0; qt < 2; ++qt) {
      f32x4 s[4];
      #pragma unroll
      for (int mtS = 0; mtS < 4; ++mtS) {
        f32x4 z = {0.f, 0.f, 0.f, 0.f};
        s[mtS] = __builtin_amdgcn_mfma_f32_16x16x32_bf16(aq[hf * 2 + qt], bk[mtS], z, 0, 0, 0);
      }
      #pragma unroll
      for (int r = 0; r < 4; ++r) {
        float v0 = s[0][r], v1 = s[1][r], v2 = s[2][r], v3 = s[3][r];
        float mx = fmaxf(fmaxf(v0, v1), fmaxf(v2, v3));
        mx = fmaxf(mx, __shfl_xor(mx, 1));
        mx = fmaxf(mx, __shfl_xor(mx, 2));
        mx = fmaxf(mx, __shfl_xor(mx, 4));
        mx = fmaxf(mx, __shfl_xor(mx, 8));
        float e0 = __expf(v0 - mx), e1 = __expf(v1 - mx);
        float e2 = __expf(v2 - mx), e3 = __expf(v3 - mx);
        float sm = e0 + e1 + e2 + e3;
        sm += __shfl_xor(sm, 1);
        sm += __shfl_xor(sm, 2);
        sm += __shfl_xor(sm, 4);
        sm += __shfl_xor(sm, 8);
        float inv = 1.0f / sm;
        int nl = qt * 16 + l4 * 4 + r;          // local row 0..31
        int sw = (nl & 7) << 4;
        *(ushort_t*)(smem + scr + ((nl * 128 + (0 * 16 + l15) * 2) ^ sw)) = f2bf(e0 * inv);
        *(ushort_t*)(smem + scr + ((nl * 128 + (1 * 16 + l15) * 2) ^ sw)) = f2bf(e1 * inv);
        *(ushort_t*)(smem + scr + ((nl * 128 + (2 * 16 + l15) * 2) ^ sw)) = f2bf(e2 * inv);
        *(ushort_t*)(smem + scr + ((nl * 128 + (3 * 16 + l15) * 2) ^ sw)) = f2bf(e3 * inv);
      }
    }
    // O += P V  (accumulate in registers)
    #pragma unroll
    for (int kt = 0; kt < 2; ++kt)
      #pragma unroll
      for (int rt = 0; rt < 2; ++rt) {
        int nl   = rt * 16 + l15;
        int byte = scr + ((nl * 128 + (kt * 32 + l4 * 8) * 2) ^ ((nl & 7) << 4));
        bf16x8 ap = *(const bf16x8*)(smem + byte);
        #pragma unroll
        for (int vt = 0; vt < 2; ++vt)
          oacc[hf][rt][vt] =
              __builtin_amdgcn_mfma_f32_16x16x32_bf16(ap, bv[vt][kt], oacc[hf][rt][vt], 0, 0, 0);
      }
  }
  __syncthreads();   // all waves past Xt reads & own scratch -> overlay Ot onto Xt region

  // write Ot[64 tok][128 c] bf16 at base 0
  #pragma unroll
  for (int hf = 0; hf < 2; ++hf)
    #pragma unroll
    for (int rt = 0; rt < 2; ++rt)
      #pragma unroll
      for (int vt = 0; vt < 2; ++vt)
        #pragma unroll
        for (int r = 0; r < 4; ++r) {
          int tok  = hf * 32 + rt * 16 + l4 * 4 + r;
          int c    = wv * 32 + vt * 16 + l15;
          int byte = (tok * 256 + c * 2) ^ ((tok & 7) << 4);
          *(ushort_t*)(smem + byte) = f2bf(oacc[hf][rt][vt][r]);
        }
  __syncthreads();

  // ---------------- Phase D: proj GEMM (acc in regs; Ot re-read per use) ----------------
  f32x4 pacc[2][4];  // [o-tile][tok-tile]
  #pragma unroll
  for (int i = 0; i < 2; ++i) {
    #pragma unroll
    for (int mt = 0; mt < 4; ++mt) pacc[i][mt] = (f32x4){0.f, 0.f, 0.f, 0.f};
    int orow0 = (wv * 2 + i) * 16;
    #pragma unroll
    for (int kt = 0; kt < 4; ++kt) {
      bf16x8 bf = *(const bf16x8*)(wproj + (size_t)(orow0 + l15) * 128 + kt * 32 + l4 * 8);
      #pragma unroll
      for (int mt = 0; mt < 4; ++mt)
        pacc[i][mt] = __builtin_amdgcn_mfma_f32_16x16x32_bf16(XT_AFRAG(mt, kt), bf, pacc[i][mt], 0, 0, 0);
    }
  }

  // ---------------- Phase E: stage f32 in scratch region + bias + coalesced writeout ----------------
  #pragma unroll
  for (int half = 0; half < 2; ++half) {
    __syncthreads();               // previous half's reads (or phase D) done
    #pragma unroll
    for (int i = 0; i < 2; ++i) {
      int o = (wv * 2 + i) * 16 + l15;
      #pragma unroll
      for (int m2 = 0; m2 < 2; ++m2)
        #pragma unroll
        for (int r = 0; r < 4; ++r) {
          int ytok = m2 * 16 + l4 * 4 + r;        // 0..31 within half
          int byte = SCR_BASE + ((ytok * 512 + o * 4) ^ ((ytok & 7) << 4));
          *(float*)(smem + byte) = pacc[i][half * 2 + m2][r];
        }
    }
    __syncthreads();
    #pragma unroll
    for (int it = 0; it < 2; ++it) {
      int idx = tid + it * 256;       // 512 tasks: (o 128) x (ty 4)
      int o   = idx & 127;
      int ty  = idx >> 7;             // 0..3
      float bias = bproj[o];
      float vals[8];
      #pragma unroll
      for (int tx = 0; tx < 8; ++tx) {
        int ytok = ty * 8 + tx;
        int byte = SCR_BASE + ((ytok * 512 + o * 4) ^ ((ytok & 7) << 4));
        vals[tx] = *(const float*)(smem + byte) + bias;
      }
      int row = half * 4 + ty;
      float4 f0 = {vals[0], vals[1], vals[2], vals[3]};
      float4 f1 = {vals[4], vals[5], vals[6], vals[7]};
      float* po = out + (((size_t)(b * 128 + o) * HH + gy0 + row) * WWID + gx0);
      *(float4*)po       = f0;
      *(float4*)(po + 4) = f1;
    }
  }
}

extern "C" void kernel_launch(void* const* d_in, const int* in_sizes, int n_in,
                              void* d_out, int out_size, void* d_ws, size_t ws_size,
                              hipStream_t stream) {
  const float* x     = (const float*)d_in[0];
  const float* wqkv  = (const float*)d_in[1];
  const float* wproj = (const float*)d_in[2];
  const float* bproj = (const float*)d_in[3];
  float* out = (float*)d_out;

  ushort_t* wbf = (ushort_t*)d_ws;   // 65536 bf16 = 128 KiB scratch
  prep_weights<<<256, 256, 0, stream>>>(wqkv, wproj, wbf);
  winattn_main<<<8192, 256, 0, stream>>>(x, wbf, wbf + 49152, bproj, out);
}

// Round 4
// 297.646 us; speedup vs baseline: 1.8711x; 1.3958x over previous
//
#include <hip/hip_runtime.h>

// WindowAttention: B=8, C=128, H=W=256, ws=8, heads=4, d=32, n=64 tokens/window
// One block = one window (8192 blocks, 256 thr = 4 waves). Wave h owns head h.
// All GEMMs via v_mfma_f32_16x16x32_bf16, f32 accumulation; softmax/bias/output f32.
// LDS = 32 KiB:
//   [0,16K):   Xt[64][128]bf16 (live A->B->D)  -> Ot[64][128]bf16 (C->D)
//   [16K,32K): per-wave 4KiB scratch (K/Q/V/P sequential, B->C)
//              -> Ystage[32][128]f32 halves (E)
// __launch_bounds__(256,2): the ONLY allocation regime measured spill-free
// (r0: VGPR=88, WRITE=263MB). (256,4)/waves_per_eu(4,4) both forced VGPR=64
// + ~0.5GB scratch spill traffic (r1/r2).

#define HH    256
#define WWID  256
#define SCALE 0.17677669529663687f

typedef float  f32x4  __attribute__((ext_vector_type(4)));
typedef __bf16 bf16x8 __attribute__((ext_vector_type(8)));
typedef short  s16x4  __attribute__((ext_vector_type(4)));
typedef unsigned short ushort_t;

#define SCR_BASE 16384

__device__ __forceinline__ ushort_t f2bf(float x) {
  unsigned u = __float_as_uint(x);
  u += 0x7fffu + ((u >> 16) & 1u);        // round-to-nearest-even
  return (ushort_t)(u >> 16);
}

__global__ void prep_weights(const float* __restrict__ wqkv,
                             const float* __restrict__ wproj,
                             ushort_t* __restrict__ wbf) {
  int i = blockIdx.x * 256 + threadIdx.x;          // 65536 total
  float v = (i < 49152) ? wqkv[i] : wproj[i - 49152];
  wbf[i] = f2bf(v);
}

__global__ __launch_bounds__(256, 2)
void winattn_main(const float* __restrict__ x,
                  const ushort_t* __restrict__ wqkv,   // [384][128] bf16
                  const ushort_t* __restrict__ wproj,  // [128][128] bf16
                  const float* __restrict__ bproj,
                  float* __restrict__ out) {
  __shared__ __align__(16) char smem[32768];

  const int tid  = threadIdx.x;
  const int lane = tid & 63;
  const int wv   = tid >> 6;       // wave id == head id
  const int l15  = lane & 15;
  const int l4   = lane >> 4;

  // XCD-aware swizzle: XCD k owns batch k; horizontally adjacent windows
  // (sharing 64B lines of x/out) are 8 apart in bid -> same XCD, adjacent in time.
  const int bid = blockIdx.x;
  const int win = ((bid & 7) << 10) | (bid >> 3);
  const int b   = win >> 10;
  const int wy  = (win >> 5) & 31;
  const int wx  = win & 31;
  const int gy0 = wy * 8, gx0 = wx * 8;

  // ---------------- Phase A: load window -> Xt[tok][c] bf16 (swizzled) ----------------
  #pragma unroll
  for (int it = 0; it < 4; ++it) {
    int idx   = tid + it * 256;        // 1024 tasks: (cpair 64) x (ty 8) x (tx4 2)
    int cpair = idx >> 4;
    int r     = idx & 15;
    int ty    = r >> 1, tx4 = r & 1;
    const float* px = x + (((size_t)(b * 128 + 2 * cpair) * HH + gy0 + ty) * WWID + gx0 + tx4 * 4);
    float4 v0 = *(const float4*)px;
    float4 v1 = *(const float4*)(px + (size_t)HH * WWID);
    float a0[4] = {v0.x, v0.y, v0.z, v0.w};
    float a1[4] = {v1.x, v1.y, v1.z, v1.w};
    #pragma unroll
    for (int i = 0; i < 4; ++i) {
      int tok = ty * 8 + tx4 * 4 + i;
      unsigned wword = (unsigned)f2bf(a0[i]) | ((unsigned)f2bf(a1[i]) << 16);
      int byte = (tok * 256 + cpair * 4) ^ ((tok & 7) << 4);
      *(unsigned*)(smem + byte) = wword;
    }
  }
  __syncthreads();

  const int scr = SCR_BASE + wv * 4096;   // private 4 KiB per wave
  bf16x8 bk[4], aq[4], bv[2][2];

  // A-fragment of Xt, re-read per use (Xt stays live through phases B and D)
  #define XT_AFRAG(mt, kt) \
    (*(const bf16x8*)(smem + ((((mt) * 16 + l15) * 256 + ((kt) * 32 + l4 * 8) * 2) ^ \
                              ((((mt) * 16 + l15) & 7) << 4))))

  // ---------------- Phase B: QKV for head wv (scratch reused K->Q->V) ----------------
  // K (weight rows 128..255), token-major [64][32]
  #pragma unroll
  for (int nt2 = 0; nt2 < 2; ++nt2) {
    int orow0 = 128 + wv * 32 + nt2 * 16;
    f32x4 acc[4] = {};
    #pragma unroll
    for (int kt = 0; kt < 4; ++kt) {
      bf16x8 bf = *(const bf16x8*)(wqkv + (size_t)(orow0 + l15) * 128 + kt * 32 + l4 * 8);
      #pragma unroll
      for (int mt = 0; mt < 4; ++mt)
        acc[mt] = __builtin_amdgcn_mfma_f32_16x16x32_bf16(XT_AFRAG(mt, kt), bf, acc[mt], 0, 0, 0);
    }
    int dloc = nt2 * 16 + l15;
    #pragma unroll
    for (int mt = 0; mt < 4; ++mt)
      #pragma unroll
      for (int r = 0; r < 4; ++r) {
        int tok  = mt * 16 + l4 * 4 + r;
        int byte = scr + ((tok * 64 + dloc * 2) ^ ((tok & 3) << 4));
        *(ushort_t*)(smem + byte) = f2bf(acc[mt][r]);
      }
  }
  #pragma unroll
  for (int mtS = 0; mtS < 4; ++mtS) {      // K B-fragments
    int m    = mtS * 16 + l15;
    int byte = scr + ((m * 64 + l4 * 16) ^ ((m & 3) << 4));
    bk[mtS] = *(const bf16x8*)(smem + byte);
  }
  // Q (weight rows 0..127), SCALE folded in
  #pragma unroll
  for (int nt2 = 0; nt2 < 2; ++nt2) {
    int orow0 = wv * 32 + nt2 * 16;
    f32x4 acc[4] = {};
    #pragma unroll
    for (int kt = 0; kt < 4; ++kt) {
      bf16x8 bf = *(const bf16x8*)(wqkv + (size_t)(orow0 + l15) * 128 + kt * 32 + l4 * 8);
      #pragma unroll
      for (int mt = 0; mt < 4; ++mt)
        acc[mt] = __builtin_amdgcn_mfma_f32_16x16x32_bf16(XT_AFRAG(mt, kt), bf, acc[mt], 0, 0, 0);
    }
    int dloc = nt2 * 16 + l15;
    #pragma unroll
    for (int mt = 0; mt < 4; ++mt)
      #pragma unroll
      for (int r = 0; r < 4; ++r) {
        int tok  = mt * 16 + l4 * 4 + r;
        int byte = scr + ((tok * 64 + dloc * 2) ^ ((tok & 3) << 4));
        *(ushort_t*)(smem + byte) = f2bf(acc[mt][r] * SCALE);
      }
  }
  #pragma unroll
  for (int t = 0; t < 4; ++t) {            // Q A-fragments (t = hf*2+qt)
    int tok  = t * 16 + l15;
    int byte = scr + ((tok * 64 + l4 * 16) ^ ((tok & 3) << 4));
    aq[t] = *(const bf16x8*)(smem + byte);
  }
  // V (weight rows 256..383), stored transposed [32 d][64 tok]
  #pragma unroll
  for (int nt2 = 0; nt2 < 2; ++nt2) {
    int orow0 = 256 + wv * 32 + nt2 * 16;
    f32x4 acc[4] = {};
    #pragma unroll
    for (int kt = 0; kt < 4; ++kt) {
      bf16x8 bf = *(const bf16x8*)(wqkv + (size_t)(orow0 + l15) * 128 + kt * 32 + l4 * 8);
      #pragma unroll
      for (int mt = 0; mt < 4; ++mt)
        acc[mt] = __builtin_amdgcn_mfma_f32_16x16x32_bf16(XT_AFRAG(mt, kt), bf, acc[mt], 0, 0, 0);
    }
    int dloc = nt2 * 16 + l15;
    #pragma unroll
    for (int mt = 0; mt < 4; ++mt) {
      int tok0 = mt * 16 + l4 * 4;
      s16x4 wv4;
      #pragma unroll
      for (int r = 0; r < 4; ++r) wv4[r] = (short)f2bf(acc[mt][r]);
      int byte = scr + ((dloc * 128 + tok0 * 2) ^ ((dloc & 7) << 4));
      *(s16x4*)(smem + byte) = wv4;
    }
  }
  #pragma unroll
  for (int vt = 0; vt < 2; ++vt)           // V B-fragments
    #pragma unroll
    for (int kt = 0; kt < 2; ++kt) {
      int d    = vt * 16 + l15;
      int byte = scr + ((d * 128 + (kt * 32 + l4 * 8) * 2) ^ ((d & 7) << 4));
      bv[vt][kt] = *(const bf16x8*)(smem + byte);
    }

  // ---------------- Phase C: attention (two 32-row halves; P overlays scratch) ----------------
  f32x4 oacc[2][2][2] = {};   // [half][row-tile][d-tile]
  #pragma unroll
  for (int hf = 0; hf < 2; ++hf) {
    #pragma unroll
    for (int qt = 0; qt < 2; ++qt) {
      f32x4 s[4];
      #pragma unroll
      for (int mtS = 0; mtS < 4; ++mtS) {
        f32x4 z = {0.f, 0.f, 0.f, 0.f};
        s[mtS] = __builtin_amdgcn_mfma_f32_16x16x32_bf16(aq[hf * 2 + qt], bk[mtS], z, 0, 0, 0);
      }
      #pragma unroll
      for (int r = 0; r < 4; ++r) {
        float v0 = s[0][r], v1 = s[1][r], v2 = s[2][r], v3 = s[3][r];
        float mx = fmaxf(fmaxf(v0, v1), fmaxf(v2, v3));
        mx = fmaxf(mx, __shfl_xor(mx, 1));
        mx = fmaxf(mx, __shfl_xor(mx, 2));
        mx = fmaxf(mx, __shfl_xor(mx, 4));
        mx = fmaxf(mx, __shfl_xor(mx, 8));
        float e0 = __expf(v0 - mx), e1 = __expf(v1 - mx);
        float e2 = __expf(v2 - mx), e3 = __expf(v3 - mx);
        float sm = e0 + e1 + e2 + e3;
        sm += __shfl_xor(sm, 1);
        sm += __shfl_xor(sm, 2);
        sm += __shfl_xor(sm, 4);
        sm += __shfl_xor(sm, 8);
        float inv = 1.0f / sm;
        int nl = qt * 16 + l4 * 4 + r;          // local row 0..31
        int sw = (nl & 7) << 4;
        *(ushort_t*)(smem + scr + ((nl * 128 + (0 * 16 + l15) * 2) ^ sw)) = f2bf(e0 * inv);
        *(ushort_t*)(smem + scr + ((nl * 128 + (1 * 16 + l15) * 2) ^ sw)) = f2bf(e1 * inv);
        *(ushort_t*)(smem + scr + ((nl * 128 + (2 * 16 + l15) * 2) ^ sw)) = f2bf(e2 * inv);
        *(ushort_t*)(smem + scr + ((nl * 128 + (3 * 16 + l15) * 2) ^ sw)) = f2bf(e3 * inv);
      }
    }
    // O += P V  (accumulate in registers)
    #pragma unroll
    for (int kt = 0; kt < 2; ++kt)
      #pragma unroll
      for (int rt = 0; rt < 2; ++rt) {
        int nl   = rt * 16 + l15;
        int byte = scr + ((nl * 128 + (kt * 32 + l4 * 8) * 2) ^ ((nl & 7) << 4));
        bf16x8 ap = *(const bf16x8*)(smem + byte);
        #pragma unroll
        for (int vt = 0; vt < 2; ++vt)
          oacc[hf][rt][vt] =
              __builtin_amdgcn_mfma_f32_16x16x32_bf16(ap, bv[vt][kt], oacc[hf][rt][vt], 0, 0, 0);
      }
  }
  __syncthreads();   // all waves past Xt reads & own scratch -> overlay Ot onto Xt region

  // write Ot[64 tok][128 c] bf16 at base 0
  #pragma unroll
  for (int hf = 0; hf < 2; ++hf)
    #pragma unroll
    for (int rt = 0; rt < 2; ++rt)
      #pragma unroll
      for (int vt = 0; vt < 2; ++vt)
        #pragma unroll
        for (int r = 0; r < 4; ++r) {
          int tok  = hf * 32 + rt * 16 + l4 * 4 + r;
          int c    = wv * 32 + vt * 16 + l15;
          int byte = (tok * 256 + c * 2) ^ ((tok & 7) << 4);
          *(ushort_t*)(smem + byte) = f2bf(oacc[hf][rt][vt][r]);
        }
  __syncthreads();

  // ---------------- Phase D: proj GEMM (acc in regs; Ot re-read per use) ----------------
  f32x4 pacc[2][4];  // [o-tile][tok-tile]
  #pragma unroll
  for (int i = 0; i < 2; ++i) {
    #pragma unroll
    for (int mt = 0; mt < 4; ++mt) pacc[i][mt] = (f32x4){0.f, 0.f, 0.f, 0.f};
    int orow0 = (wv * 2 + i) * 16;
    #pragma unroll
    for (int kt = 0; kt < 4; ++kt) {
      bf16x8 bf = *(const bf16x8*)(wproj + (size_t)(orow0 + l15) * 128 + kt * 32 + l4 * 8);
      #pragma unroll
      for (int mt = 0; mt < 4; ++mt)
        pacc[i][mt] = __builtin_amdgcn_mfma_f32_16x16x32_bf16(XT_AFRAG(mt, kt), bf, pacc[i][mt], 0, 0, 0);
    }
  }

  // ---------------- Phase E: stage f32 in scratch region + bias + coalesced writeout ----------------
  #pragma unroll
  for (int half = 0; half < 2; ++half) {
    __syncthreads();               // previous half's reads (or phase C scratch reads) done
    #pragma unroll
    for (int i = 0; i < 2; ++i) {
      int o = (wv * 2 + i) * 16 + l15;
      #pragma unroll
      for (int m2 = 0; m2 < 2; ++m2)
        #pragma unroll
        for (int r = 0; r < 4; ++r) {
          int ytok = m2 * 16 + l4 * 4 + r;        // 0..31 within half
          int byte = SCR_BASE + ((ytok * 512 + o * 4) ^ ((ytok & 7) << 4));
          *(float*)(smem + byte) = pacc[i][half * 2 + m2][r];
        }
    }
    __syncthreads();
    #pragma unroll
    for (int it = 0; it < 2; ++it) {
      int idx = tid + it * 256;       // 512 tasks: (o 128) x (ty 4)
      int o   = idx & 127;
      int ty  = idx >> 7;             // 0..3
      float bias = bproj[o];
      float vals[8];
      #pragma unroll
      for (int tx = 0; tx < 8; ++tx) {
        int ytok = ty * 8 + tx;
        int byte = SCR_BASE + ((ytok * 512 + o * 4) ^ ((ytok & 7) << 4));
        vals[tx] = *(const float*)(smem + byte) + bias;
      }
      int row = half * 4 + ty;
      float4 f0 = {vals[0], vals[1], vals[2], vals[3]};
      float4 f1 = {vals[4], vals[5], vals[6], vals[7]};
      float* po = out + (((size_t)(b * 128 + o) * HH + gy0 + row) * WWID + gx0);
      *(float4*)po       = f0;
      *(float4*)(po + 4) = f1;
    }
  }
}

extern "C" void kernel_launch(void* const* d_in, const int* in_sizes, int n_in,
                              void* d_out, int out_size, void* d_ws, size_t ws_size,
                              hipStream_t stream) {
  const float* x     = (const float*)d_in[0];
  const float* wqkv  = (const float*)d_in[1];
  const float* wproj = (const float*)d_in[2];
  const float* bproj = (const float*)d_in[3];
  float* out = (float*)d_out;

  ushort_t* wbf = (ushort_t*)d_ws;   // 65536 bf16 = 128 KiB scratch
  prep_weights<<<256, 256, 0, stream>>>(wqkv, wproj, wbf);
  winattn_main<<<8192, 256, 0, stream>>>(x, wbf, wbf + 49152, bproj, out);
}

// Round 5
// 253.360 us; speedup vs baseline: 2.1981x; 1.1748x over previous
//
#include <hip/hip_runtime.h>

// WindowAttention: B=8, C=128, H=W=256, ws=8, heads=4, d=32, n=64 tokens/window
// One block = one window (8192 blocks, 256 thr = 4 waves). Wave h owns head h.
// All GEMMs via v_mfma_f32_16x16x32_bf16, f32 accumulation.
// Key trick: A and B fragment lane-mappings are identical for 16x16x32, so
// swapping operands transposes the output tile for free. Q/K projection and
// QK^T are computed swapped (packed LDS stores; lane-local softmax rows).
// LDS = 32 KiB: [0,16K) Xt[64][128]bf16 -> Ot ; [16K,32K) per-wave 4K scratch
// (K -> Q -> V -> P serial reuse). Output written directly from regs (float4).
// __launch_bounds__(256,2): only spill-free regime measured (r0/r3 vs r1/r2).

#define HH    256
#define WWID  256
#define SCALE 0.17677669529663687f

typedef float  f32x4  __attribute__((ext_vector_type(4)));
typedef __bf16 bf16x8 __attribute__((ext_vector_type(8)));
typedef __bf16 bf16x4 __attribute__((ext_vector_type(4)));
typedef __bf16 bf16x2 __attribute__((ext_vector_type(2)));

#define SCR_BASE 16384

__global__ void prep_weights(const float* __restrict__ wqkv,
                             const float* __restrict__ wproj,
                             __bf16* __restrict__ wbf) {
  int i = blockIdx.x * 256 + threadIdx.x;          // 65536 total
  float v = (i < 49152) ? wqkv[i] : wproj[i - 49152];
  if (i < 16384) v *= SCALE;                       // fold softmax scale into Wq
  wbf[i] = (__bf16)v;
}

__global__ __launch_bounds__(256, 2)
void winattn_main(const float* __restrict__ x,
                  const __bf16* __restrict__ wqkv,   // [384][128] bf16 (Q rows pre-scaled)
                  const __bf16* __restrict__ wproj,  // [128][128] bf16
                  const float* __restrict__ bproj,
                  float* __restrict__ out) {
  __shared__ __align__(16) char smem[32768];

  const int tid  = threadIdx.x;
  const int lane = tid & 63;
  const int wv   = tid >> 6;       // wave id == head id
  const int l15  = lane & 15;
  const int l4   = lane >> 4;

  // XCD-aware swizzle: XCD k owns batch k; horizontally adjacent windows
  // (sharing 64B lines of x/out) are 8 apart in bid -> same XCD, adjacent in time.
  const int bid = blockIdx.x;
  const int win = ((bid & 7) << 10) | (bid >> 3);
  const int b   = win >> 10;
  const int wy  = (win >> 5) & 31;
  const int wx  = win & 31;
  const int gy0 = wy * 8, gx0 = wx * 8;

  // ---------------- Phase A: load window -> Xt[tok][c] bf16 (swizzled) ----------------
  #pragma unroll
  for (int it = 0; it < 4; ++it) {
    int idx   = tid + it * 256;        // 1024 tasks: (cpair 64) x (ty 8) x (tx4 2)
    int cpair = idx >> 4;
    int r     = idx & 15;
    int ty    = r >> 1, tx4 = r & 1;
    const float* px = x + (((size_t)(b * 128 + 2 * cpair) * HH + gy0 + ty) * WWID + gx0 + tx4 * 4);
    float4 v0 = *(const float4*)px;
    float4 v1 = *(const float4*)(px + (size_t)HH * WWID);
    float a0[4] = {v0.x, v0.y, v0.z, v0.w};
    float a1[4] = {v1.x, v1.y, v1.z, v1.w};
    #pragma unroll
    for (int i = 0; i < 4; ++i) {
      int tok = ty * 8 + tx4 * 4 + i;
      bf16x2 w2 = {(__bf16)a0[i], (__bf16)a1[i]};
      int byte = (tok * 256 + cpair * 4) ^ ((tok & 7) << 4);
      *(bf16x2*)(smem + byte) = w2;
    }
  }
  __syncthreads();

  const int scr = SCR_BASE + wv * 4096;   // private 4 KiB per wave
  bf16x8 bk[4], aq[4], bv[2][2];

  // Xt (and later Ot) fragment, identical mapping for A- or B-operand use.
  #define XT_AFRAG(mt, kt) \
    (*(const bf16x8*)(smem + ((((mt) * 16 + l15) * 256 + ((kt) * 32 + l4 * 8) * 2) ^ \
                              ((((mt) * 16 + l15) & 7) << 4))))

  // ---------------- Phase B1: Q & K fused, SWAPPED (D[orow][tok]) ----------------
  {
    f32x4 accQ[2][4] = {}, accK[2][4] = {};   // [nt2][mt]
    #pragma unroll
    for (int kt = 0; kt < 4; ++kt) {
      bf16x8 xf[4];
      #pragma unroll
      for (int mt = 0; mt < 4; ++mt) xf[mt] = XT_AFRAG(mt, kt);
      #pragma unroll
      for (int nt2 = 0; nt2 < 2; ++nt2) {
        bf16x8 wq = *(const bf16x8*)(wqkv + (size_t)(wv * 32 + nt2 * 16 + l15) * 128 + kt * 32 + l4 * 8);
        bf16x8 wk = *(const bf16x8*)(wqkv + (size_t)(128 + wv * 32 + nt2 * 16 + l15) * 128 + kt * 32 + l4 * 8);
        #pragma unroll
        for (int mt = 0; mt < 4; ++mt) {
          accQ[nt2][mt] = __builtin_amdgcn_mfma_f32_16x16x32_bf16(wq, xf[mt], accQ[nt2][mt], 0, 0, 0);
          accK[nt2][mt] = __builtin_amdgcn_mfma_f32_16x16x32_bf16(wk, xf[mt], accK[nt2][mt], 0, 0, 0);
        }
      }
    }
    // store K token-major [64 tok][32 d], packed 4-d writes; lane: tok=mt*16+l15, d=nt2*16+l4*4+r
    #pragma unroll
    for (int nt2 = 0; nt2 < 2; ++nt2)
      #pragma unroll
      for (int mt = 0; mt < 4; ++mt) {
        int tok = mt * 16 + l15;
        bf16x4 kp = {(__bf16)accK[nt2][mt][0], (__bf16)accK[nt2][mt][1],
                     (__bf16)accK[nt2][mt][2], (__bf16)accK[nt2][mt][3]};
        int byte = scr + ((tok * 64 + (nt2 * 16 + l4 * 4) * 2) ^ ((tok & 3) << 4));
        *(bf16x4*)(smem + byte) = kp;
      }
    #pragma unroll
    for (int mtS = 0; mtS < 4; ++mtS) {      // K fragments
      int m    = mtS * 16 + l15;
      int byte = scr + ((m * 64 + l4 * 16) ^ ((m & 3) << 4));
      bk[mtS] = *(const bf16x8*)(smem + byte);
    }
    // store Q (overwrite same scratch), then read aq
    #pragma unroll
    for (int nt2 = 0; nt2 < 2; ++nt2)
      #pragma unroll
      for (int mt = 0; mt < 4; ++mt) {
        int tok = mt * 16 + l15;
        bf16x4 qp = {(__bf16)accQ[nt2][mt][0], (__bf16)accQ[nt2][mt][1],
                     (__bf16)accQ[nt2][mt][2], (__bf16)accQ[nt2][mt][3]};
        int byte = scr + ((tok * 64 + (nt2 * 16 + l4 * 4) * 2) ^ ((tok & 3) << 4));
        *(bf16x4*)(smem + byte) = qp;
      }
    #pragma unroll
    for (int t = 0; t < 4; ++t) {            // Q fragments (t = hf*2+qt)
      int tok  = t * 16 + l15;
      int byte = scr + ((tok * 64 + l4 * 16) ^ ((tok & 3) << 4));
      aq[t] = *(const bf16x8*)(smem + byte);
    }
  }

  // ---------------- Phase B2: V (non-swapped; D[tok][d]) -> stored [32 d][64 tok] ----------------
  {
    f32x4 accV[2][4] = {};   // [nt2][mt]
    #pragma unroll
    for (int kt = 0; kt < 4; ++kt) {
      bf16x8 xf[4];
      #pragma unroll
      for (int mt = 0; mt < 4; ++mt) xf[mt] = XT_AFRAG(mt, kt);
      #pragma unroll
      for (int nt2 = 0; nt2 < 2; ++nt2) {
        bf16x8 wf = *(const bf16x8*)(wqkv + (size_t)(256 + wv * 32 + nt2 * 16 + l15) * 128 + kt * 32 + l4 * 8);
        #pragma unroll
        for (int mt = 0; mt < 4; ++mt)
          accV[nt2][mt] = __builtin_amdgcn_mfma_f32_16x16x32_bf16(xf[mt], wf, accV[nt2][mt], 0, 0, 0);
      }
    }
    #pragma unroll
    for (int nt2 = 0; nt2 < 2; ++nt2) {
      int dloc = nt2 * 16 + l15;
      #pragma unroll
      for (int mt = 0; mt < 4; ++mt) {       // lane: tok0=mt*16+l4*4, 4 consecutive toks
        int tok0 = mt * 16 + l4 * 4;
        bf16x4 vp = {(__bf16)accV[nt2][mt][0], (__bf16)accV[nt2][mt][1],
                     (__bf16)accV[nt2][mt][2], (__bf16)accV[nt2][mt][3]};
        int byte = scr + ((dloc * 128 + tok0 * 2) ^ ((dloc & 7) << 4));
        *(bf16x4*)(smem + byte) = vp;
      }
    }
    #pragma unroll
    for (int vt = 0; vt < 2; ++vt)           // V fragments
      #pragma unroll
      for (int kt = 0; kt < 2; ++kt) {
        int d    = vt * 16 + l15;
        int byte = scr + ((d * 128 + (kt * 32 + l4 * 8) * 2) ^ ((d & 7) << 4));
        bv[vt][kt] = *(const bf16x8*)(smem + byte);
      }
  }

  // ---------------- Phase C: attention, SWAPPED QK^T (lane-local softmax rows) ----------------
  f32x4 oacc[2][2][2] = {};   // [half][row-tile][d-tile]
  #pragma unroll
  for (int hf = 0; hf < 2; ++hf) {
    #pragma unroll
    for (int qt = 0; qt < 2; ++qt) {
      // S^T tile: st[mtS] = mfma(K, Q) -> D[key][q]; lane: q=qt*16+l15, key=mtS*16+l4*4+r
      f32x4 st[4];
      #pragma unroll
      for (int mtS = 0; mtS < 4; ++mtS) {
        f32x4 z = {0.f, 0.f, 0.f, 0.f};
        st[mtS] = __builtin_amdgcn_mfma_f32_16x16x32_bf16(bk[mtS], aq[hf * 2 + qt], z, 0, 0, 0);
      }
      // row softmax: 16 local values + reduce across 4 lanes (xor 16, 32)
      float mx = st[0][0];
      #pragma unroll
      for (int mtS = 0; mtS < 4; ++mtS)
        #pragma unroll
        for (int r = 0; r < 4; ++r) mx = fmaxf(mx, st[mtS][r]);
      mx = fmaxf(mx, __shfl_xor(mx, 16));
      mx = fmaxf(mx, __shfl_xor(mx, 32));
      float p[4][4];
      float sm = 0.f;
      #pragma unroll
      for (int mtS = 0; mtS < 4; ++mtS)
        #pragma unroll
        for (int r = 0; r < 4; ++r) {
          p[mtS][r] = __expf(st[mtS][r] - mx);
          sm += p[mtS][r];
        }
      sm += __shfl_xor(sm, 16);
      sm += __shfl_xor(sm, 32);
      float inv = 1.0f / sm;
      int qrow = qt * 16 + l15;               // local row 0..31 within half
      int sw   = (qrow & 7) << 4;
      #pragma unroll
      for (int mtS = 0; mtS < 4; ++mtS) {     // packed 4-key stores
        bf16x4 pp = {(__bf16)(p[mtS][0] * inv), (__bf16)(p[mtS][1] * inv),
                     (__bf16)(p[mtS][2] * inv), (__bf16)(p[mtS][3] * inv)};
        int byte = scr + ((qrow * 128 + (mtS * 16 + l4 * 4) * 2) ^ sw);
        *(bf16x4*)(smem + byte) = pp;
      }
    }
    // O += P V  (accumulate in registers)
    #pragma unroll
    for (int kt = 0; kt < 2; ++kt)
      #pragma unroll
      for (int rt = 0; rt < 2; ++rt) {
        int nl   = rt * 16 + l15;
        int byte = scr + ((nl * 128 + (kt * 32 + l4 * 8) * 2) ^ ((nl & 7) << 4));
        bf16x8 ap = *(const bf16x8*)(smem + byte);
        #pragma unroll
        for (int vt = 0; vt < 2; ++vt)
          oacc[hf][rt][vt] =
              __builtin_amdgcn_mfma_f32_16x16x32_bf16(ap, bv[vt][kt], oacc[hf][rt][vt], 0, 0, 0);
      }
  }
  __syncthreads();   // all waves past their last Xt read -> overlay Ot onto Xt region

  // write Ot[64 tok][128 c] bf16 at base 0
  #pragma unroll
  for (int hf = 0; hf < 2; ++hf)
    #pragma unroll
    for (int rt = 0; rt < 2; ++rt)
      #pragma unroll
      for (int vt = 0; vt < 2; ++vt)
        #pragma unroll
        for (int r = 0; r < 4; ++r) {
          int tok  = hf * 32 + rt * 16 + l4 * 4 + r;
          int c    = wv * 32 + vt * 16 + l15;
          int byte = (tok * 256 + c * 2) ^ ((tok & 7) << 4);
          *(__bf16*)(smem + byte) = (__bf16)oacc[hf][rt][vt][r];
        }
  __syncthreads();

  // ---------------- Phase D: proj GEMM (fused kt-loop; Ot frags shared across o-tiles) ----------------
  f32x4 pacc[2][4] = {};  // [o-tile][tok-tile]
  #pragma unroll
  for (int kt = 0; kt < 4; ++kt) {
    bf16x8 of[4];
    #pragma unroll
    for (int mt = 0; mt < 4; ++mt) of[mt] = XT_AFRAG(mt, kt);
    #pragma unroll
    for (int i = 0; i < 2; ++i) {
      bf16x8 wp = *(const bf16x8*)(wproj + (size_t)((wv * 2 + i) * 16 + l15) * 128 + kt * 32 + l4 * 8);
      #pragma unroll
      for (int mt = 0; mt < 4; ++mt)
        pacc[i][mt] = __builtin_amdgcn_mfma_f32_16x16x32_bf16(of[mt], wp, pacc[i][mt], 0, 0, 0);
    }
  }

  // ---------------- Phase E: direct float4 writeout + bias (no staging, no barriers) ----------------
  #pragma unroll
  for (int i = 0; i < 2; ++i) {
    int o = (wv * 2 + i) * 16 + l15;
    float bias = bproj[o];
    float* obase = out + (size_t)(b * 128 + o) * ((size_t)HH * WWID) + gy0 * WWID + gx0;
    #pragma unroll
    for (int mt = 0; mt < 4; ++mt) {
      int tok0 = mt * 16 + l4 * 4;            // 4 consecutive toks within one y-row
      int ty = tok0 >> 3, tx0 = tok0 & 7;
      float4 f = {pacc[i][mt][0] + bias, pacc[i][mt][1] + bias,
                  pacc[i][mt][2] + bias, pacc[i][mt][3] + bias};
      *(float4*)(obase + ty * WWID + tx0) = f;
    }
  }
}

extern "C" void kernel_launch(void* const* d_in, const int* in_sizes, int n_in,
                              void* d_out, int out_size, void* d_ws, size_t ws_size,
                              hipStream_t stream) {
  const float* x     = (const float*)d_in[0];
  const float* wqkv  = (const float*)d_in[1];
  const float* wproj = (const float*)d_in[2];
  const float* bproj = (const float*)d_in[3];
  float* out = (float*)d_out;

  __bf16* wbf = (__bf16*)d_ws;   // 65536 bf16 = 128 KiB scratch
  prep_weights<<<256, 256, 0, stream>>>(wqkv, wproj, wbf);
  winattn_main<<<8192, 256, 0, stream>>>(x, wbf, wbf + 49152, bproj, out);
}

// Round 6
// 244.293 us; speedup vs baseline: 2.2797x; 1.0371x over previous
//
#include <hip/hip_runtime.h>

// WindowAttention: B=8, C=128, H=W=256, ws=8, heads=4, d=32, n=64 tokens/window
// One block = one window (8192 blocks, 256 thr = 4 waves). Wave h owns head h.
// All GEMMs via v_mfma_f32_16x16x32_bf16, f32 accumulation.
// Swapped-operand trick: A/B fragment lane-mappings are identical for 16x16x32,
// so mfma(W, X) transposes the output for free -> packed LDS stores, lane-local
// softmax rows. SCALE*log2e folded into Wq; softmax uses v_exp_f32 (2^x) + v_rcp.
// LDS = 32 KiB: [0,16K) Xt[64][128]bf16 (256B rows, XOR-swz (tok&15)<<4) -> Ot ;
// [16K,32K) per-wave 4K scratch (K -> Q -> V -> P serial reuse; 64B rows &3,
// 128B rows &7). Output written directly from regs (float4).
// __launch_bounds__(256,2): only spill-free regime measured (r0/r3 vs r1/r2).

#define HH    256
#define WWID  256
#define SCALE 0.17677669529663687f
#define LOG2E 1.44269504088896340736f

typedef float  f32x4  __attribute__((ext_vector_type(4)));
typedef __bf16 bf16x8 __attribute__((ext_vector_type(8)));
typedef __bf16 bf16x4 __attribute__((ext_vector_type(4)));
typedef __bf16 bf16x2 __attribute__((ext_vector_type(2)));

#define SCR_BASE 16384

__global__ void prep_weights(const float* __restrict__ wqkv,
                             const float* __restrict__ wproj,
                             __bf16* __restrict__ wbf) {
  int i = blockIdx.x * 256 + threadIdx.x;          // 65536 total
  float v = (i < 49152) ? wqkv[i] : wproj[i - 49152];
  if (i < 16384) v *= SCALE * LOG2E;               // fold softmax scale + log2e into Wq
  wbf[i] = (__bf16)v;
}

__global__ __launch_bounds__(256, 2)
void winattn_main(const float* __restrict__ x,
                  const __bf16* __restrict__ wqkv,   // [384][128] bf16 (Q rows pre-scaled)
                  const __bf16* __restrict__ wproj,  // [128][128] bf16
                  const float* __restrict__ bproj,
                  float* __restrict__ out) {
  __shared__ __align__(16) char smem[32768];

  const int tid  = threadIdx.x;
  const int lane = tid & 63;
  const int wv   = tid >> 6;       // wave id == head id
  const int l15  = lane & 15;
  const int l4   = lane >> 4;

  // XCD-aware swizzle: XCD k owns batch k; horizontally adjacent windows
  // (sharing 64B lines of x/out) are 8 apart in bid -> same XCD, adjacent in time.
  const int bid = blockIdx.x;
  const int win = ((bid & 7) << 10) | (bid >> 3);
  const int b   = win >> 10;
  const int wy  = (win >> 5) & 31;
  const int wx  = win & 31;
  const int gy0 = wy * 8, gx0 = wx * 8;

  // ---------------- Phase A: load window -> Xt[tok][c] bf16 (swizzled &15) ----------------
  #pragma unroll
  for (int it = 0; it < 4; ++it) {
    int idx   = tid + it * 256;        // 1024 tasks: (cpair 64) x (ty 8) x (tx4 2)
    int cpair = idx >> 4;
    int r     = idx & 15;
    int ty    = r >> 1, tx4 = r & 1;
    const float* px = x + (((size_t)(b * 128 + 2 * cpair) * HH + gy0 + ty) * WWID + gx0 + tx4 * 4);
    float4 v0 = *(const float4*)px;
    float4 v1 = *(const float4*)(px + (size_t)HH * WWID);
    float a0[4] = {v0.x, v0.y, v0.z, v0.w};
    float a1[4] = {v1.x, v1.y, v1.z, v1.w};
    #pragma unroll
    for (int i = 0; i < 4; ++i) {
      int tok = ty * 8 + tx4 * 4 + i;
      bf16x2 w2 = {(__bf16)a0[i], (__bf16)a1[i]};
      int byte = (tok * 256 + cpair * 4) ^ ((tok & 15) << 4);
      *(bf16x2*)(smem + byte) = w2;
    }
  }
  __syncthreads();

  const int scr = SCR_BASE + wv * 4096;   // private 4 KiB per wave
  bf16x8 bk[4], aq[4], bv[2][2];

  // Xt (and later Ot) fragment, identical mapping for A- or B-operand use.
  #define XT_AFRAG(mt, kt) \
    (*(const bf16x8*)(smem + ((((mt) * 16 + l15) * 256 + ((kt) * 32 + l4 * 8) * 2) ^ \
                              ((((mt) * 16 + l15) & 15) << 4))))

  // ---------------- Phase B1: Q & K fused, SWAPPED (D[orow][tok]) ----------------
  {
    f32x4 accQ[2][4] = {}, accK[2][4] = {};   // [nt2][mt]
    __builtin_amdgcn_s_setprio(1);
    #pragma unroll
    for (int kt = 0; kt < 4; ++kt) {
      bf16x8 xf[4];
      #pragma unroll
      for (int mt = 0; mt < 4; ++mt) xf[mt] = XT_AFRAG(mt, kt);
      #pragma unroll
      for (int nt2 = 0; nt2 < 2; ++nt2) {
        bf16x8 wq = *(const bf16x8*)(wqkv + (size_t)(wv * 32 + nt2 * 16 + l15) * 128 + kt * 32 + l4 * 8);
        bf16x8 wk = *(const bf16x8*)(wqkv + (size_t)(128 + wv * 32 + nt2 * 16 + l15) * 128 + kt * 32 + l4 * 8);
        #pragma unroll
        for (int mt = 0; mt < 4; ++mt) {
          accQ[nt2][mt] = __builtin_amdgcn_mfma_f32_16x16x32_bf16(wq, xf[mt], accQ[nt2][mt], 0, 0, 0);
          accK[nt2][mt] = __builtin_amdgcn_mfma_f32_16x16x32_bf16(wk, xf[mt], accK[nt2][mt], 0, 0, 0);
        }
      }
    }
    __builtin_amdgcn_s_setprio(0);
    // store K token-major [64 tok][32 d], packed 4-d writes; lane: tok=mt*16+l15, d=nt2*16+l4*4+r
    #pragma unroll
    for (int nt2 = 0; nt2 < 2; ++nt2)
      #pragma unroll
      for (int mt = 0; mt < 4; ++mt) {
        int tok = mt * 16 + l15;
        bf16x4 kp = {(__bf16)accK[nt2][mt][0], (__bf16)accK[nt2][mt][1],
                     (__bf16)accK[nt2][mt][2], (__bf16)accK[nt2][mt][3]};
        int byte = scr + ((tok * 64 + (nt2 * 16 + l4 * 4) * 2) ^ ((tok & 3) << 4));
        *(bf16x4*)(smem + byte) = kp;
      }
    #pragma unroll
    for (int mtS = 0; mtS < 4; ++mtS) {      // K fragments
      int m    = mtS * 16 + l15;
      int byte = scr + ((m * 64 + l4 * 16) ^ ((m & 3) << 4));
      bk[mtS] = *(const bf16x8*)(smem + byte);
    }
    // store Q (overwrite same scratch), then read aq
    #pragma unroll
    for (int nt2 = 0; nt2 < 2; ++nt2)
      #pragma unroll
      for (int mt = 0; mt < 4; ++mt) {
        int tok = mt * 16 + l15;
        bf16x4 qp = {(__bf16)accQ[nt2][mt][0], (__bf16)accQ[nt2][mt][1],
                     (__bf16)accQ[nt2][mt][2], (__bf16)accQ[nt2][mt][3]};
        int byte = scr + ((tok * 64 + (nt2 * 16 + l4 * 4) * 2) ^ ((tok & 3) << 4));
        *(bf16x4*)(smem + byte) = qp;
      }
    #pragma unroll
    for (int t = 0; t < 4; ++t) {            // Q fragments (t = hf*2+qt)
      int tok  = t * 16 + l15;
      int byte = scr + ((tok * 64 + l4 * 16) ^ ((tok & 3) << 4));
      aq[t] = *(const bf16x8*)(smem + byte);
    }
  }

  // ---------------- Phase B2: V (non-swapped; D[tok][d]) -> stored [32 d][64 tok] ----------------
  {
    f32x4 accV[2][4] = {};   // [nt2][mt]
    __builtin_amdgcn_s_setprio(1);
    #pragma unroll
    for (int kt = 0; kt < 4; ++kt) {
      bf16x8 xf[4];
      #pragma unroll
      for (int mt = 0; mt < 4; ++mt) xf[mt] = XT_AFRAG(mt, kt);
      #pragma unroll
      for (int nt2 = 0; nt2 < 2; ++nt2) {
        bf16x8 wf = *(const bf16x8*)(wqkv + (size_t)(256 + wv * 32 + nt2 * 16 + l15) * 128 + kt * 32 + l4 * 8);
        #pragma unroll
        for (int mt = 0; mt < 4; ++mt)
          accV[nt2][mt] = __builtin_amdgcn_mfma_f32_16x16x32_bf16(xf[mt], wf, accV[nt2][mt], 0, 0, 0);
      }
    }
    __builtin_amdgcn_s_setprio(0);
    #pragma unroll
    for (int nt2 = 0; nt2 < 2; ++nt2) {
      int dloc = nt2 * 16 + l15;
      #pragma unroll
      for (int mt = 0; mt < 4; ++mt) {       // lane: tok0=mt*16+l4*4, 4 consecutive toks
        int tok0 = mt * 16 + l4 * 4;
        bf16x4 vp = {(__bf16)accV[nt2][mt][0], (__bf16)accV[nt2][mt][1],
                     (__bf16)accV[nt2][mt][2], (__bf16)accV[nt2][mt][3]};
        int byte = scr + ((dloc * 128 + tok0 * 2) ^ ((dloc & 7) << 4));
        *(bf16x4*)(smem + byte) = vp;
      }
    }
    #pragma unroll
    for (int vt = 0; vt < 2; ++vt)           // V fragments
      #pragma unroll
      for (int kt = 0; kt < 2; ++kt) {
        int d    = vt * 16 + l15;
        int byte = scr + ((d * 128 + (kt * 32 + l4 * 8) * 2) ^ ((d & 7) << 4));
        bv[vt][kt] = *(const bf16x8*)(smem + byte);
      }
  }

  // ---------------- Phase C: attention, SWAPPED QK^T (lane-local softmax rows) ----------------
  f32x4 oacc[2][2][2] = {};   // [half][row-tile][d-tile]
  #pragma unroll
  for (int hf = 0; hf < 2; ++hf) {
    #pragma unroll
    for (int qt = 0; qt < 2; ++qt) {
      // S^T tile: st[mtS] = mfma(K, Q) -> D[key][q]; lane: q=qt*16+l15, key=mtS*16+l4*4+r
      f32x4 st[4];
      __builtin_amdgcn_s_setprio(1);
      #pragma unroll
      for (int mtS = 0; mtS < 4; ++mtS) {
        f32x4 z = {0.f, 0.f, 0.f, 0.f};
        st[mtS] = __builtin_amdgcn_mfma_f32_16x16x32_bf16(bk[mtS], aq[hf * 2 + qt], z, 0, 0, 0);
      }
      __builtin_amdgcn_s_setprio(0);
      // row softmax in log2 domain (scale*log2e pre-folded into Wq)
      float mx = st[0][0];
      #pragma unroll
      for (int mtS = 0; mtS < 4; ++mtS)
        #pragma unroll
        for (int r = 0; r < 4; ++r) mx = fmaxf(mx, st[mtS][r]);
      mx = fmaxf(mx, __shfl_xor(mx, 16));
      mx = fmaxf(mx, __shfl_xor(mx, 32));
      float p[4][4];
      float sm = 0.f;
      #pragma unroll
      for (int mtS = 0; mtS < 4; ++mtS)
        #pragma unroll
        for (int r = 0; r < 4; ++r) {
          p[mtS][r] = __builtin_amdgcn_exp2f(st[mtS][r] - mx);
          sm += p[mtS][r];
        }
      sm += __shfl_xor(sm, 16);
      sm += __shfl_xor(sm, 32);
      float inv = __builtin_amdgcn_rcpf(sm);
      int qrow = qt * 16 + l15;               // local row 0..31 within half
      int sw   = (qrow & 7) << 4;
      #pragma unroll
      for (int mtS = 0; mtS < 4; ++mtS) {     // packed 4-key stores
        bf16x4 pp = {(__bf16)(p[mtS][0] * inv), (__bf16)(p[mtS][1] * inv),
                     (__bf16)(p[mtS][2] * inv), (__bf16)(p[mtS][3] * inv)};
        int byte = scr + ((qrow * 128 + (mtS * 16 + l4 * 4) * 2) ^ sw);
        *(bf16x4*)(smem + byte) = pp;
      }
    }
    // O += P V  (accumulate in registers)
    __builtin_amdgcn_s_setprio(1);
    #pragma unroll
    for (int kt = 0; kt < 2; ++kt)
      #pragma unroll
      for (int rt = 0; rt < 2; ++rt) {
        int nl   = rt * 16 + l15;
        int byte = scr + ((nl * 128 + (kt * 32 + l4 * 8) * 2) ^ ((nl & 7) << 4));
        bf16x8 ap = *(const bf16x8*)(smem + byte);
        #pragma unroll
        for (int vt = 0; vt < 2; ++vt)
          oacc[hf][rt][vt] =
              __builtin_amdgcn_mfma_f32_16x16x32_bf16(ap, bv[vt][kt], oacc[hf][rt][vt], 0, 0, 0);
      }
    __builtin_amdgcn_s_setprio(0);
  }
  __syncthreads();   // all waves past their last Xt read -> overlay Ot onto Xt region

  // write Ot[64 tok][128 c] bf16 at base 0 (swz &15: 2-way, free)
  #pragma unroll
  for (int hf = 0; hf < 2; ++hf)
    #pragma unroll
    for (int rt = 0; rt < 2; ++rt)
      #pragma unroll
      for (int vt = 0; vt < 2; ++vt)
        #pragma unroll
        for (int r = 0; r < 4; ++r) {
          int tok  = hf * 32 + rt * 16 + l4 * 4 + r;
          int c    = wv * 32 + vt * 16 + l15;
          int byte = (tok * 256 + c * 2) ^ ((tok & 15) << 4);
          *(__bf16*)(smem + byte) = (__bf16)oacc[hf][rt][vt][r];
        }
  __syncthreads();

  // ---------------- Phase D: proj GEMM (fused kt-loop; Ot frags shared across o-tiles) ----------------
  f32x4 pacc[2][4] = {};  // [o-tile][tok-tile]
  __builtin_amdgcn_s_setprio(1);
  #pragma unroll
  for (int kt = 0; kt < 4; ++kt) {
    bf16x8 of[4];
    #pragma unroll
    for (int mt = 0; mt < 4; ++mt) of[mt] = XT_AFRAG(mt, kt);
    #pragma unroll
    for (int i = 0; i < 2; ++i) {
      bf16x8 wp = *(const bf16x8*)(wproj + (size_t)((wv * 2 + i) * 16 + l15) * 128 + kt * 32 + l4 * 8);
      #pragma unroll
      for (int mt = 0; mt < 4; ++mt)
        pacc[i][mt] = __builtin_amdgcn_mfma_f32_16x16x32_bf16(of[mt], wp, pacc[i][mt], 0, 0, 0);
    }
  }
  __builtin_amdgcn_s_setprio(0);

  // ---------------- Phase E: direct float4 writeout + bias (no staging, no barriers) ----------------
  #pragma unroll
  for (int i = 0; i < 2; ++i) {
    int o = (wv * 2 + i) * 16 + l15;
    float bias = bproj[o];
    float* obase = out + (size_t)(b * 128 + o) * ((size_t)HH * WWID) + gy0 * WWID + gx0;
    #pragma unroll
    for (int mt = 0; mt < 4; ++mt) {
      int tok0 = mt * 16 + l4 * 4;            // 4 consecutive toks within one y-row
      int ty = tok0 >> 3, tx0 = tok0 & 7;
      float4 f = {pacc[i][mt][0] + bias, pacc[i][mt][1] + bias,
                  pacc[i][mt][2] + bias, pacc[i][mt][3] + bias};
      *(float4*)(obase + ty * WWID + tx0) = f;
    }
  }
}

extern "C" void kernel_launch(void* const* d_in, const int* in_sizes, int n_in,
                              void* d_out, int out_size, void* d_ws, size_t ws_size,
                              hipStream_t stream) {
  const float* x     = (const float*)d_in[0];
  const float* wqkv  = (const float*)d_in[1];
  const float* wproj = (const float*)d_in[2];
  const float* bproj = (const float*)d_in[3];
  float* out = (float*)d_out;

  __bf16* wbf = (__bf16*)d_ws;   // 65536 bf16 = 128 KiB scratch
  prep_weights<<<256, 256, 0, stream>>>(wqkv, wproj, wbf);
  winattn_main<<<8192, 256, 0, stream>>>(x, wbf, wbf + 49152, bproj, out);
}